// Round 5
// baseline (141.237 us; speedup 1.0000x reference)
//
#include <hip/hip_runtime.h>
#include <math.h>

#define TOTAL 2560
#define NEG_BIG (-1e30f)

typedef __bf16 bf16x8 __attribute__((ext_vector_type(8)));
typedef float f32x4 __attribute__((ext_vector_type(4)));
typedef unsigned short ushort8v __attribute__((ext_vector_type(8)));
typedef unsigned short ushort4v __attribute__((ext_vector_type(4)));

__device__ inline unsigned short f2bf(float f) {
    unsigned u = __builtin_bit_cast(unsigned, f);
    u += 0x7fff + ((u >> 16) & 1);
    return (unsigned short)(u >> 16);
}

// ---------------- positional encoding (4 points / block) ----------------
__global__ __launch_bounds__(256) void pos_kernel(
    const float* __restrict__ coords,
    const float* __restrict__ pos_w,
    const float* __restrict__ pos_b,
    float* __restrict__ pos_out)
{
    __shared__ float enc[4][100];
    const int wv   = threadIdx.x >> 6;
    const int lane = threadIdx.x & 63;
    const int p = blockIdx.x * 4 + wv;
    const float c0 = coords[p * 3 + 0];
    const float c1 = coords[p * 3 + 1];
    const float c2 = coords[p * 3 + 2];
    for (int i = lane; i < 99; i += 64) {
        float v;
        if (i < 96) {
            const int d = i >> 5;
            const int j = i & 31;
            const float cv = (d == 0) ? c0 : ((d == 1) ? c1 : c2);
            const float freq = exp2f((float)(j & 15)) * 3.14159265358979323846f;
            const float sc = cv * freq;
            v = (j < 16) ? sinf(sc) : cosf(sc);
        } else {
            v = (i == 96) ? c0 : ((i == 97) ? c1 : c2);
        }
        enc[wv][i] = v;
    }
    // wave-local fill + wave-local read: lockstep wave, no block barrier needed
    float acc = pos_b[lane];
    const float* w = pos_w + lane * 99;
    for (int i = 0; i < 99; ++i) acc = fmaf(enc[wv][i], w[i], acc);
    pos_out[p * 64 + lane] = acc;
}

// ---------------- fp32 -> bf16 cast (features, qkv_w, proj_w) ----------------
__global__ __launch_bounds__(256) void cast_kernel(
    const float* __restrict__ f,  const float* __restrict__ qw, const float* __restrict__ pw,
    unsigned short* __restrict__ fb, unsigned short* __restrict__ qwb, unsigned short* __restrict__ pwb)
{
    const int s = blockIdx.x * 256 + threadIdx.x;
    const float* src; unsigned short* dst; int ls;
    if (s < 163840)      { src = f;  dst = fb;  ls = s; }
    else if (s < 262144) { src = qw; dst = qwb; ls = s - 163840; }
    else                 { src = pw; dst = pwb; ls = s - 262144; }
    const float4 x0 = *(const float4*)(src + ls * 8);
    const float4 x1 = *(const float4*)(src + ls * 8 + 4);
    ushort8v o;
    o[0] = f2bf(x0.x); o[1] = f2bf(x0.y); o[2] = f2bf(x0.z); o[3] = f2bf(x0.w);
    o[4] = f2bf(x1.x); o[5] = f2bf(x1.y); o[6] = f2bf(x1.z); o[7] = f2bf(x1.w);
    *(ushort8v*)(dst + ls * 8) = o;
}

// ---------------- QKV GEMM: bf16 MFMA, 128x128 tile, BK=64 ----------------
// V is written TRANSPOSED [h][d][p] (fuses old vtrans kernel).
__global__ __launch_bounds__(256) void qkv_mfma_kernel(
    const unsigned short* __restrict__ A,
    const unsigned short* __restrict__ Bm,
    const float* __restrict__ pos,
    unsigned short* __restrict__ q_ws,
    unsigned short* __restrict__ k_ws,
    unsigned short* __restrict__ vt_ws)
{
    __shared__ unsigned short A_lds[128 * 64];
    __shared__ unsigned short B_lds[128 * 64];
    const int m0 = blockIdx.x * 128;
    const int n0 = blockIdx.y * 128;
    const int t = threadIdx.x;
    const int w = t >> 6, l = t & 63;
    const int wr = w >> 1, wc = w & 1;
    const int c = l & 15, g = l >> 4;
    const int lr8 = l >> 3, cs = l & 7;

    f32x4 acc[4][4];
#pragma unroll
    for (int mi = 0; mi < 4; ++mi)
#pragma unroll
        for (int ni = 0; ni < 4; ++ni) acc[mi][ni] = (f32x4){0.f, 0.f, 0.f, 0.f};

    for (int kt = 0; kt < 8; ++kt) {
        uint4 areg[4], breg[4];
#pragma unroll
        for (int i = 0; i < 4; ++i) {
            const int row = w * 32 + i * 8 + lr8;
            areg[i] = *(const uint4*)(A  + (m0 + row) * 512 + kt * 64 + cs * 8);
            breg[i] = *(const uint4*)(Bm + (n0 + row) * 512 + kt * 64 + cs * 8);
        }
        __syncthreads();
#pragma unroll
        for (int i = 0; i < 4; ++i) {
            const int row = w * 32 + i * 8 + lr8;
            const int slot = cs ^ (row & 7);
            *(uint4*)&A_lds[row * 64 + slot * 8] = areg[i];
            *(uint4*)&B_lds[row * 64 + slot * 8] = breg[i];
        }
        __syncthreads();
#pragma unroll
        for (int kk = 0; kk < 2; ++kk) {
            bf16x8 af[4], bfr[4];
#pragma unroll
            for (int mi = 0; mi < 4; ++mi) {
                const int row = wr * 64 + mi * 16 + c;
                af[mi] = *(const bf16x8*)&A_lds[row * 64 + ((g + 4 * kk) ^ (row & 7)) * 8];
            }
#pragma unroll
            for (int ni = 0; ni < 4; ++ni) {
                const int row = wc * 64 + ni * 16 + c;
                bfr[ni] = *(const bf16x8*)&B_lds[row * 64 + ((g + 4 * kk) ^ (row & 7)) * 8];
            }
#pragma unroll
            for (int mi = 0; mi < 4; ++mi)
#pragma unroll
                for (int ni = 0; ni < 4; ++ni)
                    acc[mi][ni] = __builtin_amdgcn_mfma_f32_16x16x32_bf16(af[mi], bfr[ni], acc[mi][ni], 0, 0, 0);
        }
    }

    const int which = n0 >> 9;   // 0=q 1=k 2=v (128-col slab within one segment)
#pragma unroll
    for (int mi = 0; mi < 4; ++mi)
#pragma unroll
        for (int ni = 0; ni < 4; ++ni) {
            const int col = n0 + wc * 64 + ni * 16 + c;
            const int h = (col >> 6) & 7, dd = col & 63;
            const int p0 = m0 + wr * 64 + mi * 16 + 4 * g;
            if (which == 2) {
                ushort4v o4;
#pragma unroll
                for (int r = 0; r < 4; ++r) o4[r] = f2bf(acc[mi][ni][r]);
                *(ushort4v*)(vt_ws + (h * 64 + dd) * TOTAL + p0) = o4;
            } else {
#pragma unroll
                for (int r = 0; r < 4; ++r) {
                    const int p = p0 + r;
                    const float v = acc[mi][ni][r] + pos[p * 64 + dd];
                    const int idx = (h * TOTAL + p) * 64 + dd;
                    if (which == 0) q_ws[idx] = f2bf(v);
                    else            k_ws[idx] = f2bf(v);
                }
            }
        }
}

// ---------------- flash attention (bf16 MFMA, KVBLK=128, 2-phase) ----------------
// flat grid 320: [0,64)->batch0 (qt 0..7), [64,320)->batch1 (qt 0..31). 4 waves,
// wave w owns q rows 16w..16w+15. batch0: 512 keys + 1536 analytic zero-keys.
__global__ __launch_bounds__(256) void attn_kernel(
    const unsigned short* __restrict__ q_ws,
    const unsigned short* __restrict__ k_ws,
    const unsigned short* __restrict__ vt_ws,
    unsigned short* __restrict__ y)
{
    const int bx = blockIdx.x;
    int b, qt, h;
    if (bx < 64) { b = 0; h = bx >> 3; qt = bx & 7; }
    else         { b = 1; const int rr = bx - 64; h = rr >> 5; qt = rr & 31; }
    const int base = b ? 512 : 0;
    const int nkt  = b ? 16 : 4;                    // 128-key tiles
    const int kt0  = (b && qt < 8) ? 4 : 0;         // mask: skip k<512 for q<512
    const float extra = b ? 0.0f : 1536.0f;

    const int t    = threadIdx.x;
    const int w    = t >> 6;
    const int lane = t & 63;
    const int g    = lane >> 4;
    const int c    = lane & 15;

    __shared__ unsigned short K_lds[128][72];    // [k][d]
    __shared__ unsigned short V_lds[64][136];    // V^T tile: [d][k]
    __shared__ unsigned short P_lds[64][136];    // [q][k]

    const unsigned short* Qrow = q_ws + ((h * TOTAL) + base + qt * 64 + 16 * w + c) * 64;
    const bf16x8 qa0 = *(const bf16x8*)(Qrow + 8 * g);
    const bf16x8 qa1 = *(const bf16x8*)(Qrow + 8 * g + 32);

    float m_old[4], l_old[4];
#pragma unroll
    for (int r = 0; r < 4; ++r) { m_old[r] = NEG_BIG; l_old[r] = 0.f; }
    f32x4 o_acc[4];
#pragma unroll
    for (int n = 0; n < 4; ++n) o_acc[n] = (f32x4){0.f, 0.f, 0.f, 0.f};

    const unsigned short* Kg = k_ws + (h * TOTAL + base) * 64;
    const unsigned short* Vg = vt_ws + h * 64 * TOTAL + base;

    uint4 kreg[4], vreg[4];
    // prologue loads for first tile
#pragma unroll
    for (int i = 0; i < 4; ++i) {
        const int ek = t + i * 256;
        kreg[i] = *(const uint4*)(Kg + (kt0 * 128 + (ek >> 3)) * 64 + (ek & 7) * 8);
        const int ev = t + i * 256;
        vreg[i] = *(const uint4*)(Vg + (ev >> 4) * TOTAL + kt0 * 128 + (ev & 15) * 8);
    }

    for (int kt = kt0; kt < nkt; ++kt) {
        __syncthreads();   // previous compute finished reading LDS
#pragma unroll
        for (int i = 0; i < 4; ++i) {
            const int ek = t + i * 256;
            *(uint4*)&K_lds[ek >> 3][(ek & 7) * 8] = kreg[i];
            const int ev = t + i * 256;
            *(uint4*)&V_lds[ev >> 4][(ev & 15) * 8] = vreg[i];
        }
        __syncthreads();
        if (kt + 1 < nkt) {   // issue next tile's loads early: overlap with compute
#pragma unroll
            for (int i = 0; i < 4; ++i) {
                const int ek = t + i * 256;
                kreg[i] = *(const uint4*)(Kg + ((kt + 1) * 128 + (ek >> 3)) * 64 + (ek & 7) * 8);
                const int ev = t + i * 256;
                vreg[i] = *(const uint4*)(Vg + (ev >> 4) * TOTAL + (kt + 1) * 128 + (ev & 15) * 8);
            }
        }

        // S = Q K^T : 16 MFMAs -> s_acc[n][r] = S[q=16w+4g+r][k=16n+c]
        f32x4 s_acc[8];
#pragma unroll
        for (int n = 0; n < 8; ++n) {
            f32x4 acc = (f32x4){0.f, 0.f, 0.f, 0.f};
            const bf16x8 kb0 = *(const bf16x8*)&K_lds[16 * n + c][8 * g];
            const bf16x8 kb1 = *(const bf16x8*)&K_lds[16 * n + c][8 * g + 32];
            acc = __builtin_amdgcn_mfma_f32_16x16x32_bf16(qa0, kb0, acc, 0, 0, 0);
            acc = __builtin_amdgcn_mfma_f32_16x16x32_bf16(qa1, kb1, acc, 0, 0, 0);
            s_acc[n] = acc;
        }

        // online softmax (scaled by 0.125), stats reduced over 16 lanes (c)
        float corr[4];
#pragma unroll
        for (int r = 0; r < 4; ++r) {
            float tm = s_acc[0][r];
#pragma unroll
            for (int n = 1; n < 8; ++n) tm = fmaxf(tm, s_acc[n][r]);
            tm *= 0.125f;
            tm = fmaxf(tm, __shfl_xor(tm, 1));
            tm = fmaxf(tm, __shfl_xor(tm, 2));
            tm = fmaxf(tm, __shfl_xor(tm, 4));
            tm = fmaxf(tm, __shfl_xor(tm, 8));
            const float m_new = fmaxf(m_old[r], tm);
            corr[r] = __expf(m_old[r] - m_new);
            float rs = 0.f;
#pragma unroll
            for (int n = 0; n < 8; ++n) {
                const float pv = __expf(s_acc[n][r] * 0.125f - m_new);
                s_acc[n][r] = pv;
                rs += pv;
            }
            rs += __shfl_xor(rs, 1);
            rs += __shfl_xor(rs, 2);
            rs += __shfl_xor(rs, 4);
            rs += __shfl_xor(rs, 8);
            l_old[r] = l_old[r] * corr[r] + rs;
            m_old[r] = m_new;
        }

        // write P (wave-local rows: no block barrier needed), rescale O
#pragma unroll
        for (int n = 0; n < 8; ++n)
#pragma unroll
            for (int r = 0; r < 4; ++r)
                P_lds[16 * w + 4 * g + r][16 * n + c] = f2bf(s_acc[n][r]);
#pragma unroll
        for (int n = 0; n < 4; ++n)
#pragma unroll
            for (int r = 0; r < 4; ++r) o_acc[n][r] *= corr[r];

        // O += P V : 16 MFMAs
#pragma unroll
        for (int kk = 0; kk < 4; ++kk) {
            const bf16x8 pa = *(const bf16x8*)&P_lds[16 * w + c][8 * g + 32 * kk];
#pragma unroll
            for (int n = 0; n < 4; ++n) {
                const bf16x8 vb = *(const bf16x8*)&V_lds[16 * n + c][8 * g + 32 * kk];
                o_acc[n] = __builtin_amdgcn_mfma_f32_16x16x32_bf16(pa, vb, o_acc[n], 0, 0, 0);
            }
        }
    }

    // finalize: analytic zero-score keys (batch0) + normalize
    float inv[4];
#pragma unroll
    for (int r = 0; r < 4; ++r) {
        float m = m_old[r], l = l_old[r], so = 1.f;
        if (extra > 0.f) {
            const float mn = fmaxf(m, 0.f);
            const float ccf = __expf(m - mn);
            l = l * ccf + extra * __expf(-mn);
            so = ccf;
        }
        inv[r] = so / l;
    }
    unsigned short* yb = y + (base + qt * 64 + 16 * w) * 512 + h * 64;
#pragma unroll
    for (int n = 0; n < 4; ++n)
#pragma unroll
        for (int r = 0; r < 4; ++r)
            yb[(4 * g + r) * 512 + 16 * n + c] = f2bf(o_acc[n][r] * inv[r]);
}

// ---------------- output projection: bf16 MFMA + bias, fp32 out ----------------
__global__ __launch_bounds__(256) void proj_mfma_kernel(
    const unsigned short* __restrict__ A,    // y_bf [2560][512]
    const unsigned short* __restrict__ Bm,   // projw_bf [512][512]
    const float* __restrict__ bias,
    float* __restrict__ out)
{
    __shared__ unsigned short A_lds[128 * 64];
    __shared__ unsigned short B_lds[128 * 64];
    const int m0 = blockIdx.x * 128;
    const int n0 = blockIdx.y * 128;
    const int t = threadIdx.x;
    const int w = t >> 6, l = t & 63;
    const int wr = w >> 1, wc = w & 1;
    const int c = l & 15, g = l >> 4;
    const int lr8 = l >> 3, cs = l & 7;

    f32x4 acc[4][4];
#pragma unroll
    for (int mi = 0; mi < 4; ++mi)
#pragma unroll
        for (int ni = 0; ni < 4; ++ni) acc[mi][ni] = (f32x4){0.f, 0.f, 0.f, 0.f};

    for (int kt = 0; kt < 8; ++kt) {
        uint4 areg[4], breg[4];
#pragma unroll
        for (int i = 0; i < 4; ++i) {
            const int row = w * 32 + i * 8 + lr8;
            areg[i] = *(const uint4*)(A  + (m0 + row) * 512 + kt * 64 + cs * 8);
            breg[i] = *(const uint4*)(Bm + (n0 + row) * 512 + kt * 64 + cs * 8);
        }
        __syncthreads();
#pragma unroll
        for (int i = 0; i < 4; ++i) {
            const int row = w * 32 + i * 8 + lr8;
            const int slot = cs ^ (row & 7);
            *(uint4*)&A_lds[row * 64 + slot * 8] = areg[i];
            *(uint4*)&B_lds[row * 64 + slot * 8] = breg[i];
        }
        __syncthreads();
#pragma unroll
        for (int kk = 0; kk < 2; ++kk) {
            bf16x8 af[4], bfr[4];
#pragma unroll
            for (int mi = 0; mi < 4; ++mi) {
                const int row = wr * 64 + mi * 16 + c;
                af[mi] = *(const bf16x8*)&A_lds[row * 64 + ((g + 4 * kk) ^ (row & 7)) * 8];
            }
#pragma unroll
            for (int ni = 0; ni < 4; ++ni) {
                const int row = wc * 64 + ni * 16 + c;
                bfr[ni] = *(const bf16x8*)&B_lds[row * 64 + ((g + 4 * kk) ^ (row & 7)) * 8];
            }
#pragma unroll
            for (int mi = 0; mi < 4; ++mi)
#pragma unroll
                for (int ni = 0; ni < 4; ++ni)
                    acc[mi][ni] = __builtin_amdgcn_mfma_f32_16x16x32_bf16(af[mi], bfr[ni], acc[mi][ni], 0, 0, 0);
        }
    }

#pragma unroll
    for (int mi = 0; mi < 4; ++mi)
#pragma unroll
        for (int ni = 0; ni < 4; ++ni) {
            const int col = n0 + wc * 64 + ni * 16 + c;
            const float bv = bias[col];
#pragma unroll
            for (int r = 0; r < 4; ++r) {
                const int p = m0 + wr * 64 + mi * 16 + 4 * g + r;
                out[p * 512 + col] = acc[mi][ni][r] + bv;
            }
        }
}

extern "C" void kernel_launch(void* const* d_in, const int* in_sizes, int n_in,
                              void* d_out, int out_size, void* d_ws, size_t ws_size,
                              hipStream_t stream) {
    const float* features = (const float*)d_in[0];
    const float* coords   = (const float*)d_in[1];
    const float* qkv_w    = (const float*)d_in[2];
    const float* proj_w   = (const float*)d_in[3];
    const float* proj_b   = (const float*)d_in[4];
    const float* pos_w    = (const float*)d_in[5];
    const float* pos_b    = (const float*)d_in[6];
    float* out = (float*)d_out;

    float* pos_ws = (float*)d_ws;                                    // 2560*64 f32
    unsigned short* feat_bf  = (unsigned short*)(pos_ws + TOTAL * 64);
    unsigned short* qkvw_bf  = feat_bf + 2560 * 512;
    unsigned short* projw_bf = qkvw_bf + 1536 * 512;
    unsigned short* q_ws  = projw_bf + 512 * 512;
    unsigned short* k_ws  = q_ws  + 8 * TOTAL * 64;
    unsigned short* vt_ws = k_ws  + 8 * TOTAL * 64;
    unsigned short* y_bf  = vt_ws + 8 * TOTAL * 64;

    pos_kernel<<<dim3(TOTAL / 4), dim3(256), 0, stream>>>(coords, pos_w, pos_b, pos_ws);
    cast_kernel<<<dim3(1152), dim3(256), 0, stream>>>(
        features, qkv_w, proj_w, feat_bf, qkvw_bf, projw_bf);
    qkv_mfma_kernel<<<dim3(2560 / 128, 1536 / 128), dim3(256), 0, stream>>>(
        feat_bf, qkvw_bf, pos_ws, q_ws, k_ws, vt_ws);
    attn_kernel<<<dim3(320), dim3(256), 0, stream>>>(q_ws, k_ws, vt_ws, y_bf);
    proj_mfma_kernel<<<dim3(2560 / 128, 512 / 128), dim3(256), 0, stream>>>(
        y_bf, projw_bf, proj_b, out);
}

// Round 6
// 112.716 us; speedup vs baseline: 1.2530x; 1.2530x over previous
//
#include <hip/hip_runtime.h>
#include <math.h>

#define TOTAL 2560
#define NEG_BIG (-1e30f)

typedef __bf16 bf16x8 __attribute__((ext_vector_type(8)));
typedef float f32x4 __attribute__((ext_vector_type(4)));
typedef unsigned short ushort8v __attribute__((ext_vector_type(8)));
typedef unsigned short ushort4v __attribute__((ext_vector_type(4)));

__device__ inline unsigned short f2bf(float f) {
    unsigned u = __builtin_bit_cast(unsigned, f);
    u += 0x7fff + ((u >> 16) & 1);
    return (unsigned short)(u >> 16);
}

__device__ inline void gload16(const void* g, void* l) {
    __builtin_amdgcn_global_load_lds(
        (const __attribute__((address_space(1))) void*)g,
        (__attribute__((address_space(3))) void*)l, 16, 0, 0);
}

// ---------------- positional encoding (4 points / block) ----------------
__global__ __launch_bounds__(256) void pos_kernel(
    const float* __restrict__ coords,
    const float* __restrict__ pos_w,
    const float* __restrict__ pos_b,
    float* __restrict__ pos_out)
{
    __shared__ float enc[4][100];
    const int wv   = threadIdx.x >> 6;
    const int lane = threadIdx.x & 63;
    const int p = blockIdx.x * 4 + wv;
    const float c0 = coords[p * 3 + 0];
    const float c1 = coords[p * 3 + 1];
    const float c2 = coords[p * 3 + 2];
    for (int i = lane; i < 99; i += 64) {
        float v;
        if (i < 96) {
            const int d = i >> 5;
            const int j = i & 31;
            const float cv = (d == 0) ? c0 : ((d == 1) ? c1 : c2);
            const float freq = exp2f((float)(j & 15)) * 3.14159265358979323846f;
            const float sc = cv * freq;
            v = (j < 16) ? sinf(sc) : cosf(sc);
        } else {
            v = (i == 96) ? c0 : ((i == 97) ? c1 : c2);
        }
        enc[wv][i] = v;
    }
    float acc = pos_b[lane];
    const float* w = pos_w + lane * 99;
    for (int i = 0; i < 99; ++i) acc = fmaf(enc[wv][i], w[i], acc);
    pos_out[p * 64 + lane] = acc;
}

// ---------------- fp32 -> bf16 cast (features, qkv_w, proj_w) ----------------
__global__ __launch_bounds__(256) void cast_kernel(
    const float* __restrict__ f,  const float* __restrict__ qw, const float* __restrict__ pw,
    unsigned short* __restrict__ fb, unsigned short* __restrict__ qwb, unsigned short* __restrict__ pwb)
{
    const int s = blockIdx.x * 256 + threadIdx.x;
    const float* src; unsigned short* dst; int ls;
    if (s < 163840)      { src = f;  dst = fb;  ls = s; }
    else if (s < 262144) { src = qw; dst = qwb; ls = s - 163840; }
    else                 { src = pw; dst = pwb; ls = s - 262144; }
    const float4 x0 = *(const float4*)(src + ls * 8);
    const float4 x1 = *(const float4*)(src + ls * 8 + 4);
    ushort8v o;
    o[0] = f2bf(x0.x); o[1] = f2bf(x0.y); o[2] = f2bf(x0.z); o[3] = f2bf(x0.w);
    o[4] = f2bf(x1.x); o[5] = f2bf(x1.y); o[6] = f2bf(x1.z); o[7] = f2bf(x1.w);
    *(ushort8v*)(dst + ls * 8) = o;
}

// ---------------- QKV GEMM: bf16 MFMA, 128x128 tile, BK=64 ----------------
// V is written TRANSPOSED [h][d][p].
__global__ __launch_bounds__(256) void qkv_mfma_kernel(
    const unsigned short* __restrict__ A,
    const unsigned short* __restrict__ Bm,
    const float* __restrict__ pos,
    unsigned short* __restrict__ q_ws,
    unsigned short* __restrict__ k_ws,
    unsigned short* __restrict__ vt_ws)
{
    __shared__ unsigned short A_lds[128 * 64];
    __shared__ unsigned short B_lds[128 * 64];
    const int m0 = blockIdx.x * 128;
    const int n0 = blockIdx.y * 128;
    const int t = threadIdx.x;
    const int w = t >> 6, l = t & 63;
    const int wr = w >> 1, wc = w & 1;
    const int c = l & 15, g = l >> 4;
    const int lr8 = l >> 3, cs = l & 7;

    f32x4 acc[4][4];
#pragma unroll
    for (int mi = 0; mi < 4; ++mi)
#pragma unroll
        for (int ni = 0; ni < 4; ++ni) acc[mi][ni] = (f32x4){0.f, 0.f, 0.f, 0.f};

    for (int kt = 0; kt < 8; ++kt) {
        uint4 areg[4], breg[4];
#pragma unroll
        for (int i = 0; i < 4; ++i) {
            const int row = w * 32 + i * 8 + lr8;
            areg[i] = *(const uint4*)(A  + (m0 + row) * 512 + kt * 64 + cs * 8);
            breg[i] = *(const uint4*)(Bm + (n0 + row) * 512 + kt * 64 + cs * 8);
        }
        __syncthreads();
#pragma unroll
        for (int i = 0; i < 4; ++i) {
            const int row = w * 32 + i * 8 + lr8;
            const int slot = cs ^ (row & 7);
            *(uint4*)&A_lds[row * 64 + slot * 8] = areg[i];
            *(uint4*)&B_lds[row * 64 + slot * 8] = breg[i];
        }
        __syncthreads();
#pragma unroll
        for (int kk = 0; kk < 2; ++kk) {
            bf16x8 af[4], bfr[4];
#pragma unroll
            for (int mi = 0; mi < 4; ++mi) {
                const int row = wr * 64 + mi * 16 + c;
                af[mi] = *(const bf16x8*)&A_lds[row * 64 + ((g + 4 * kk) ^ (row & 7)) * 8];
            }
#pragma unroll
            for (int ni = 0; ni < 4; ++ni) {
                const int row = wc * 64 + ni * 16 + c;
                bfr[ni] = *(const bf16x8*)&B_lds[row * 64 + ((g + 4 * kk) ^ (row & 7)) * 8];
            }
#pragma unroll
            for (int mi = 0; mi < 4; ++mi)
#pragma unroll
                for (int ni = 0; ni < 4; ++ni)
                    acc[mi][ni] = __builtin_amdgcn_mfma_f32_16x16x32_bf16(af[mi], bfr[ni], acc[mi][ni], 0, 0, 0);
        }
    }

    const int which = n0 >> 9;   // 0=q 1=k 2=v
#pragma unroll
    for (int mi = 0; mi < 4; ++mi)
#pragma unroll
        for (int ni = 0; ni < 4; ++ni) {
            const int col = n0 + wc * 64 + ni * 16 + c;
            const int h = (col >> 6) & 7, dd = col & 63;
            const int p0 = m0 + wr * 64 + mi * 16 + 4 * g;
            if (which == 2) {
                ushort4v o4;
#pragma unroll
                for (int r = 0; r < 4; ++r) o4[r] = f2bf(acc[mi][ni][r]);
                *(ushort4v*)(vt_ws + (h * 64 + dd) * TOTAL + p0) = o4;
            } else {
#pragma unroll
                for (int r = 0; r < 4; ++r) {
                    const int p = p0 + r;
                    const float v = acc[mi][ni][r] + pos[p * 64 + dd];
                    const int idx = (h * TOTAL + p) * 64 + dd;
                    if (which == 0) q_ws[idx] = f2bf(v);
                    else            k_ws[idx] = f2bf(v);
                }
            }
        }
}

// ---------------- flash attention (bf16 MFMA, KVBLK=128, gload_lds pipeline) ----
// flat grid 320: [0,64)->batch0 (qt 0..7), [64,320)->batch1 (qt 0..31). 4 waves,
// wave w owns q rows 16w..16w+15. batch0: 512 keys + 1536 analytic zero-keys.
// K/V double-buffered in LDS via global_load_lds with pre-swizzled global source
// (LDS[row][slot] = G[row][slot ^ (row&7)]); reads apply the same XOR.
__global__ __launch_bounds__(256) void attn_kernel(
    const unsigned short* __restrict__ q_ws,
    const unsigned short* __restrict__ k_ws,
    const unsigned short* __restrict__ vt_ws,
    unsigned short* __restrict__ y)
{
    const int bx = blockIdx.x;
    int b, qt, h;
    if (bx < 64) { b = 0; h = bx >> 3; qt = bx & 7; }
    else         { b = 1; const int rr = bx - 64; h = rr >> 5; qt = rr & 31; }
    const int base = b ? 512 : 0;
    const int nkt  = b ? 16 : 4;                    // 128-key tiles
    const int kt0  = (b && qt < 8) ? 4 : 0;         // mask: skip k<512 for q<512
    const float extra = b ? 0.0f : 1536.0f;

    const int t    = threadIdx.x;
    const int w    = t >> 6;
    const int lane = t & 63;
    const int g    = lane >> 4;
    const int c    = lane & 15;

    __shared__ unsigned short Kbuf[2][128 * 64];   // [key][d], swizzled slots
    __shared__ unsigned short Vbuf[2][64 * 128];   // [d][key], swizzled slots
    __shared__ unsigned short P_lds[64][72];       // [q][k-half]

    const unsigned short* Qrow = q_ws + ((h * TOTAL) + base + qt * 64 + 16 * w + c) * 64;
    const bf16x8 qa0 = *(const bf16x8*)(Qrow + 8 * g);
    const bf16x8 qa1 = *(const bf16x8*)(Qrow + 8 * g + 32);

    float m_old[4], l_old[4];
#pragma unroll
    for (int r = 0; r < 4; ++r) { m_old[r] = NEG_BIG; l_old[r] = 0.f; }
    f32x4 o_acc[4];
#pragma unroll
    for (int n = 0; n < 4; ++n) o_acc[n] = (f32x4){0.f, 0.f, 0.f, 0.f};

    const unsigned short* Kg = k_ws + (h * TOTAL + base) * 64;
    const unsigned short* Vg = vt_ws + h * 64 * TOTAL + base;

    // stage one 128-key tile into buf[cur]: 8 gload16 per wave (4 K + 4 V)
    auto STAGE = [&](int kt, int cur) {
#pragma unroll
        for (int i = 0; i < 4; ++i) {
            const int off = w * 4096 + i * 1024;          // byte offset, wave-uniform
            const int ba  = off + lane * 16;              // this lane's dest byte
            {   // K: 128 rows x 128 B
                const int row = ba >> 7, slot = (ba & 127) >> 4;
                gload16(Kg + (kt * 128 + row) * 64 + ((slot ^ (row & 7)) * 8),
                        (char*)&Kbuf[cur][0] + off);
            }
            {   // V: 64 rows x 256 B
                const int dd = ba >> 8, slot = (ba & 255) >> 4;
                gload16(Vg + dd * TOTAL + kt * 128 + ((slot ^ (dd & 7)) * 8),
                        (char*)&Vbuf[cur][0] + off);
            }
        }
    };

    STAGE(kt0, 0);
    int cur = 0;
    for (int kt = kt0; kt < nkt; ++kt) {
        __syncthreads();   // drains vmcnt(0): buf[cur] ready; joins previous compute
        if (kt + 1 < nkt) STAGE(kt + 1, cur ^ 1);   // overlap with compute below

        const unsigned short* Ksh = &Kbuf[cur][0];
        const unsigned short* Vsh = &Vbuf[cur][0];

        // S = Q K^T : 16 MFMAs -> s_acc[n][r] = S[q=16w+4g+r][k=16n+c]
        f32x4 s_acc[8];
#pragma unroll
        for (int n = 0; n < 8; ++n) {
            f32x4 acc = (f32x4){0.f, 0.f, 0.f, 0.f};
            const int row = 16 * n + c;
            const bf16x8 kb0 = *(const bf16x8*)&Ksh[row * 64 + ((g + 0) ^ (c & 7)) * 8];
            const bf16x8 kb1 = *(const bf16x8*)&Ksh[row * 64 + ((g + 4) ^ (c & 7)) * 8];
            acc = __builtin_amdgcn_mfma_f32_16x16x32_bf16(qa0, kb0, acc, 0, 0, 0);
            acc = __builtin_amdgcn_mfma_f32_16x16x32_bf16(qa1, kb1, acc, 0, 0, 0);
            s_acc[n] = acc;
        }

        // online softmax (scale 0.125), stats reduced over the 16 c-lanes
        float corr[4];
#pragma unroll
        for (int r = 0; r < 4; ++r) {
            float tm = s_acc[0][r];
#pragma unroll
            for (int n = 1; n < 8; ++n) tm = fmaxf(tm, s_acc[n][r]);
            tm *= 0.125f;
            tm = fmaxf(tm, __shfl_xor(tm, 1));
            tm = fmaxf(tm, __shfl_xor(tm, 2));
            tm = fmaxf(tm, __shfl_xor(tm, 4));
            tm = fmaxf(tm, __shfl_xor(tm, 8));
            const float m_new = fmaxf(m_old[r], tm);
            corr[r] = __expf(m_old[r] - m_new);
            float rs = 0.f;
#pragma unroll
            for (int n = 0; n < 8; ++n) {
                const float pv = __expf(s_acc[n][r] * 0.125f - m_new);
                s_acc[n][r] = pv;
                rs += pv;
            }
            rs += __shfl_xor(rs, 1);
            rs += __shfl_xor(rs, 2);
            rs += __shfl_xor(rs, 4);
            rs += __shfl_xor(rs, 8);
            l_old[r] = l_old[r] * corr[r] + rs;
            m_old[r] = m_new;
        }
#pragma unroll
        for (int n = 0; n < 4; ++n)
#pragma unroll
            for (int r = 0; r < 4; ++r) o_acc[n][r] *= corr[r];

        // PV in two 64-key halves through P_lds (wave-local rows: no barrier)
#pragma unroll
        for (int half = 0; half < 2; ++half) {
#pragma unroll
            for (int n = 0; n < 4; ++n)
#pragma unroll
                for (int r = 0; r < 4; ++r)
                    P_lds[16 * w + 4 * g + r][16 * n + c] = f2bf(s_acc[half * 4 + n][r]);
#pragma unroll
            for (int kk = 0; kk < 2; ++kk) {
                const bf16x8 pa = *(const bf16x8*)&P_lds[16 * w + c][8 * g + 32 * kk];
                const int vslot = (g + 4 * (half * 2 + kk)) ^ (c & 7);
#pragma unroll
                for (int n = 0; n < 4; ++n) {
                    const bf16x8 vb = *(const bf16x8*)&Vsh[(16 * n + c) * 128 + vslot * 8];
                    o_acc[n] = __builtin_amdgcn_mfma_f32_16x16x32_bf16(pa, vb, o_acc[n], 0, 0, 0);
                }
            }
        }
        cur ^= 1;
    }

    // finalize: analytic zero-score keys (batch0) + normalize
    float inv[4];
#pragma unroll
    for (int r = 0; r < 4; ++r) {
        float m = m_old[r], l = l_old[r], so = 1.f;
        if (extra > 0.f) {
            const float mn = fmaxf(m, 0.f);
            const float ccf = __expf(m - mn);
            l = l * ccf + extra * __expf(-mn);
            so = ccf;
        }
        inv[r] = so / l;
    }
    unsigned short* yb = y + (base + qt * 64 + 16 * w) * 512 + h * 64;
#pragma unroll
    for (int n = 0; n < 4; ++n)
#pragma unroll
        for (int r = 0; r < 4; ++r)
            yb[(4 * g + r) * 512 + 16 * n + c] = f2bf(o_acc[n][r] * inv[r]);
}

// ---------------- output projection: bf16 MFMA + bias, fp32 out ----------------
__global__ __launch_bounds__(256) void proj_mfma_kernel(
    const unsigned short* __restrict__ A,    // y_bf [2560][512]
    const unsigned short* __restrict__ Bm,   // projw_bf [512][512]
    const float* __restrict__ bias,
    float* __restrict__ out)
{
    __shared__ unsigned short A_lds[128 * 64];
    __shared__ unsigned short B_lds[128 * 64];
    const int m0 = blockIdx.x * 128;
    const int n0 = blockIdx.y * 128;
    const int t = threadIdx.x;
    const int w = t >> 6, l = t & 63;
    const int wr = w >> 1, wc = w & 1;
    const int c = l & 15, g = l >> 4;
    const int lr8 = l >> 3, cs = l & 7;

    f32x4 acc[4][4];
#pragma unroll
    for (int mi = 0; mi < 4; ++mi)
#pragma unroll
        for (int ni = 0; ni < 4; ++ni) acc[mi][ni] = (f32x4){0.f, 0.f, 0.f, 0.f};

    for (int kt = 0; kt < 8; ++kt) {
        uint4 areg[4], breg[4];
#pragma unroll
        for (int i = 0; i < 4; ++i) {
            const int row = w * 32 + i * 8 + lr8;
            areg[i] = *(const uint4*)(A  + (m0 + row) * 512 + kt * 64 + cs * 8);
            breg[i] = *(const uint4*)(Bm + (n0 + row) * 512 + kt * 64 + cs * 8);
        }
        __syncthreads();
#pragma unroll
        for (int i = 0; i < 4; ++i) {
            const int row = w * 32 + i * 8 + lr8;
            const int slot = cs ^ (row & 7);
            *(uint4*)&A_lds[row * 64 + slot * 8] = areg[i];
            *(uint4*)&B_lds[row * 64 + slot * 8] = breg[i];
        }
        __syncthreads();
#pragma unroll
        for (int kk = 0; kk < 2; ++kk) {
            bf16x8 af[4], bfr[4];
#pragma unroll
            for (int mi = 0; mi < 4; ++mi) {
                const int row = wr * 64 + mi * 16 + c;
                af[mi] = *(const bf16x8*)&A_lds[row * 64 + ((g + 4 * kk) ^ (row & 7)) * 8];
            }
#pragma unroll
            for (int ni = 0; ni < 4; ++ni) {
                const int row = wc * 64 + ni * 16 + c;
                bfr[ni] = *(const bf16x8*)&B_lds[row * 64 + ((g + 4 * kk) ^ (row & 7)) * 8];
            }
#pragma unroll
            for (int mi = 0; mi < 4; ++mi)
#pragma unroll
                for (int ni = 0; ni < 4; ++ni)
                    acc[mi][ni] = __builtin_amdgcn_mfma_f32_16x16x32_bf16(af[mi], bfr[ni], acc[mi][ni], 0, 0, 0);
        }
    }

#pragma unroll
    for (int mi = 0; mi < 4; ++mi)
#pragma unroll
        for (int ni = 0; ni < 4; ++ni) {
            const int col = n0 + wc * 64 + ni * 16 + c;
            const float bv = bias[col];
#pragma unroll
            for (int r = 0; r < 4; ++r) {
                const int p = m0 + wr * 64 + mi * 16 + 4 * g + r;
                out[p * 512 + col] = acc[mi][ni][r] + bv;
            }
        }
}

extern "C" void kernel_launch(void* const* d_in, const int* in_sizes, int n_in,
                              void* d_out, int out_size, void* d_ws, size_t ws_size,
                              hipStream_t stream) {
    const float* features = (const float*)d_in[0];
    const float* coords   = (const float*)d_in[1];
    const float* qkv_w    = (const float*)d_in[2];
    const float* proj_w   = (const float*)d_in[3];
    const float* proj_b   = (const float*)d_in[4];
    const float* pos_w    = (const float*)d_in[5];
    const float* pos_b    = (const float*)d_in[6];
    float* out = (float*)d_out;

    float* pos_ws = (float*)d_ws;                                    // 2560*64 f32
    unsigned short* feat_bf  = (unsigned short*)(pos_ws + TOTAL * 64);
    unsigned short* qkvw_bf  = feat_bf + 2560 * 512;
    unsigned short* projw_bf = qkvw_bf + 1536 * 512;
    unsigned short* q_ws  = projw_bf + 512 * 512;
    unsigned short* k_ws  = q_ws  + 8 * TOTAL * 64;
    unsigned short* vt_ws = k_ws  + 8 * TOTAL * 64;
    unsigned short* y_bf  = vt_ws + 8 * TOTAL * 64;

    pos_kernel<<<dim3(TOTAL / 4), dim3(256), 0, stream>>>(coords, pos_w, pos_b, pos_ws);
    cast_kernel<<<dim3(1152), dim3(256), 0, stream>>>(
        features, qkv_w, proj_w, feat_bf, qkvw_bf, projw_bf);
    qkv_mfma_kernel<<<dim3(2560 / 128, 1536 / 128), dim3(256), 0, stream>>>(
        feat_bf, qkvw_bf, pos_ws, q_ws, k_ws, vt_ws);
    attn_kernel<<<dim3(320), dim3(256), 0, stream>>>(q_ws, k_ws, vt_ws, y_bf);
    proj_mfma_kernel<<<dim3(2560 / 128, 512 / 128), dim3(256), 0, stream>>>(
        y_bf, projw_bf, proj_b, out);
}